// Round 8
// baseline (195.360 us; speedup 1.0000x reference)
//
#include <hip/hip_runtime.h>
#include <hip/hip_bf16.h>
#include <math.h>

#define N_NODES 1024
#define T_DIM 8

typedef __bf16 bf16x8 __attribute__((ext_vector_type(8)));
typedef float  f32x4  __attribute__((ext_vector_type(4)));

__device__ __forceinline__ float readlane_f(float v, int l) {
    return __uint_as_float(__builtin_amdgcn_readlane(__float_as_uint(v), l));
}

// ---- Kernel A: h = inp@W ; s1,s2 ; hT = (h*mask_j) bf16, TILE-contiguous ----
// hT layout: [bt][tile=nt][o][j'] where each (bt,nt) tile is 64x64 bf16 = 8 KB
// contiguous, and j-octets are XOR-swizzled: element (o,j) at
// o*64 + ((j>>3)^(o&7))*8 + (j&7). Kernel B stages tiles with contiguous 1KB
// loads and reads MFMA B-frags from LDS bank-conflict-free.
// mask_j folded here (hT only feeds PV; softmax denominator is unmasked).
__global__ __launch_bounds__(256) void gat_h_kernel(
    const float* __restrict__ inp, const float* __restrict__ W,
    const float* __restrict__ a, const float* __restrict__ att_mask,
    __bf16* __restrict__ hT, float* __restrict__ s1w, float* __restrict__ s2w)
{
    __shared__ float Wl[64 * 64];
    __shared__ float xl[64 * 64];
    __shared__ __bf16 htl[64 * 66];   // [o][row], stride 66 -> conflict-free transpose

    const int tid  = threadIdx.x;
    const int blk  = blockIdx.x;
    const int bt   = blk >> 4;
    const int b    = bt >> 3;
    const int t    = bt & 7;
    const int nt   = blk & 15;        // j-tile index within bt
    const int n0   = nt * 64;
    const int lane = tid & 63;        // = o in compute phase
    const int wave = tid >> 6;

    const float4* W4  = (const float4*)W;
    float4*       Wl4 = (float4*)Wl;
    const float4* x4  = (const float4*)(inp + (size_t)(bt * N_NODES + n0) * 64);
    float4*       xl4 = (float4*)xl;
#pragma unroll
    for (int k = 0; k < 4; ++k) {
        Wl4[tid + k * 256] = W4[tid + k * 256];
        xl4[tid + k * 256] = x4[tid + k * 256];
    }
    const float a1 = a[lane];
    const float a2 = a[64 + lane];
    __syncthreads();

#pragma unroll 1
    for (int rg = 0; rg < 16; rg += 4) {
        float xr[4], acc[4];
#pragma unroll
        for (int q = 0; q < 4; ++q) {
            xr[q]  = xl[(wave * 16 + rg + q) * 64 + lane];
            acc[q] = 0.f;
        }
#pragma unroll
        for (int f = 0; f < 64; ++f) {
            float w = Wl[f * 64 + lane];
#pragma unroll
            for (int q = 0; q < 4; ++q)
                acc[q] = fmaf(readlane_f(xr[q], f), w, acc[q]);
        }
#pragma unroll
        for (int q = 0; q < 4; ++q) {
            const int r = wave * 16 + rg + q;   // local row = tile-local j
            float v1 = acc[q] * a1, v2 = acc[q] * a2;
#pragma unroll
            for (int off = 32; off; off >>= 1) {
                v1 += __shfl_xor(v1, off, 64);
                v2 += __shfl_xor(v2, off, 64);
            }
            if (lane == 0) {
                s1w[bt * N_NODES + n0 + r] = v1;
                s2w[bt * N_NODES + n0 + r] = v2;
            }
            const float mjr = att_mask[((size_t)b * N_NODES + n0 + r) * T_DIM + t];
            htl[lane * 66 + r] = (__bf16)(acc[q] * mjr);
        }
    }
    __syncthreads();

    // write tile: thread (o = tid>>2, r0 = (tid&3)*16) stores j = r0..r0+15
    // as two uint4 (= octets r0>>3 and (r0>>3)+1), octet XOR-swizzled by o&7.
    {
        const int o  = tid >> 2;
        const int r0 = (tid & 3) * 16;
        const int s  = o & 7;
        unsigned u[8];
#pragma unroll
        for (int k = 0; k < 8; ++k)
            u[k] = *(const unsigned*)&htl[o * 66 + r0 + 2 * k];
        __bf16* tbase = hT + ((size_t)(bt * 16 + nt) * 64 + o) * 64;
        const int g0 = (r0 >> 3);          // even
        *(uint4*)(tbase + ((g0    ) ^ s) * 8) = make_uint4(u[0], u[1], u[2], u[3]);
        *(uint4*)(tbase + ((g0 | 1) ^ s) * 8) = make_uint4(u[4], u[5], u[6], u[7]);
    }
}

// ---- Kernel B: one-wave flash GAT, ALL VMEM contiguous ----------------------
// grid (64 i-tiles, 32 bt) x 64 thr. Per j-tile: adj = 16 coalesced 256B row
// loads (lane=j); h tile = 8 contiguous 1KB loads -> regs -> ds_write_b128 ->
// swizzled ds_read_b128 B-frags (2-way banks, free). P computed lane=j, turned
// into A-frag via wave-private LDS (r4-validated). Register prefetch 1 tile
// ahead; single wave => no barriers, precise vmcnt waits only.
__global__ __launch_bounds__(64) void gat_attn_kernel(
    const float* __restrict__ adj, const float* __restrict__ att_mask,
    const __bf16* __restrict__ hT, const float* __restrict__ s1w,
    const float* __restrict__ s2w, float* __restrict__ out)
{
    __shared__ __align__(16) __bf16 htile[64 * 64];   // [o][swizzled j], 8 KB
    __shared__ __align__(16) __bf16 p_l[16 * 72];     // [row][j], pad 72

    const int bt    = blockIdx.y;
    const int b     = bt >> 3;
    const int t     = bt & 7;
    const int irow0 = blockIdx.x * 16;
    const int lane  = threadIdx.x;      // score phase: lane = j
    const int l15   = lane & 15;
    const int quad  = lane >> 4;

    f32x4 acc[4];
#pragma unroll
    for (int nc = 0; nc < 4; ++nc) acc[nc] = (f32x4){0.f, 0.f, 0.f, 0.f};
    float lsum[16], s1v[16];
#pragma unroll
    for (int r = 0; r < 16; ++r) {
        lsum[r] = 0.f;
        s1v[r]  = s1w[bt * N_NODES + irow0 + r];
    }

    const float*  adjrow = adj + (size_t)t * N_NODES * N_NODES
                               + (size_t)irow0 * N_NODES + lane;
    const char*   tb     = (const char*)(hT + (size_t)bt * 16 * 4096); // 8KB tiles
    const float*  s2bt   = s2w + bt * N_NODES;
    __bf16* pwr = p_l + lane;                         // score write (lane = j)
    const __bf16* prd = p_l + l15 * 72 + quad * 8;    // P A-frag read
    const int swz = l15 & 7;                          // == o&7 for all nc

    // ---- preload tile 0: h as 8x contiguous 1KB, adj 16 coalesced rows, s2 --
    uint4 hreg[8];
    float adjc[16];
    float s2c;
#pragma unroll
    for (int c = 0; c < 8; ++c)
        hreg[c] = *(const uint4*)(tb + c * 1024 + lane * 16);
#pragma unroll
    for (int r = 0; r < 16; ++r) adjc[r] = adjrow[(size_t)r * N_NODES];
    s2c = s2bt[lane];

#pragma unroll 2
    for (int it = 0; it < 16; ++it) {
        const int jn = (it < 15) ? (it + 1) * 64 : 0;   // next tile (wrap unused)
        const char* tbn = tb + (size_t)(jn >> 6) * 8192;

        // ---- 1. prefetch next tile (contiguous h, coalesced adj, s2) ----
        uint4 hregn[8];
        float adjn[16];
#pragma unroll
        for (int c = 0; c < 8; ++c)
            hregn[c] = *(const uint4*)(tbn + c * 1024 + lane * 16);
#pragma unroll
        for (int r = 0; r < 16; ++r) adjn[r] = adjrow[(size_t)r * N_NODES + jn];
        const float s2n = s2bt[jn + lane];

        // ---- 2. write current h tile to LDS (sequential b128, conflict-free)
#pragma unroll
        for (int c = 0; c < 8; ++c)
            *(uint4*)((char*)htile + c * 1024 + lane * 16) = hreg[c];

        // ---- 3. scores (lane = j); leaky bounds e*adj in [-6,~16] so exp
        // never overflows -> no max pass; p -> P LDS (A-frag transpose) ----
#pragma unroll
        for (int r = 0; r < 16; ++r) {
            float e = s1v[r] + s2c;
            e = fmaxf(e, 0.2f * e);
            float p = (adjc[r] > 0.f) ? __expf(e * adjc[r]) : 0.f;
            lsum[r] += p;
            pwr[r * 72] = (__bf16)p;
        }

        // ---- 4. fragments from LDS (lgkm-precise, same wave, no barrier) ---
        bf16x8 af0 = *(const bf16x8*)(prd);
        bf16x8 af1 = *(const bf16x8*)(prd + 32);
        bf16x8 bfr[8];
#pragma unroll
        for (int kc = 0; kc < 2; ++kc)
#pragma unroll
            for (int nc = 0; nc < 4; ++nc) {
                const int o = nc * 16 + l15;
                const int g = (kc * 4 + quad) ^ swz;
                bfr[kc * 4 + nc] = *(const bf16x8*)&htile[o * 64 + g * 8];
            }

        // ---- 5. 8 MFMAs ----
#pragma unroll
        for (int nc = 0; nc < 4; ++nc)
            acc[nc] = __builtin_amdgcn_mfma_f32_16x16x32_bf16(af0, bfr[nc], acc[nc], 0, 0, 0);
#pragma unroll
        for (int nc = 0; nc < 4; ++nc)
            acc[nc] = __builtin_amdgcn_mfma_f32_16x16x32_bf16(af1, bfr[4 + nc], acc[nc], 0, 0, 0);

        // ---- 6. rotate prefetch buffers (unroll-2 renames copies away) ----
#pragma unroll
        for (int c = 0; c < 8; ++c) hreg[c] = hregn[c];
#pragma unroll
        for (int r = 0; r < 16; ++r) adjc[r] = adjn[r];
        s2c = s2n;
    }

    // ---- epilogue: reduce lsum per row, mi/ls scale + ELU + store ----
#pragma unroll
    for (int r = 0; r < 16; ++r) {
#pragma unroll
        for (int off = 32; off; off >>= 1)
            lsum[r] += __shfl_xor(lsum[r], off, 64);
    }
#pragma unroll
    for (int reg = 0; reg < 4; ++reg) {
        float ls = (quad == 0) ? lsum[reg] : (quad == 1) ? lsum[4 + reg]
                 : (quad == 2) ? lsum[8 + reg] : lsum[12 + reg];
        const int i = irow0 + quad * 4 + reg;
        float mi    = att_mask[((size_t)b * N_NODES + i) * T_DIM + t];
        float scale = mi / ls;
#pragma unroll
        for (int nc = 0; nc < 4; ++nc) {
            float v = acc[nc][reg] * scale;
            v = (v > 0.f) ? v : (__expf(v) - 1.f);
            out[((size_t)bt * N_NODES + i) * 64 + nc * 16 + l15] = v;
        }
    }
}

extern "C" void kernel_launch(void* const* d_in, const int* in_sizes, int n_in,
                              void* d_out, int out_size, void* d_ws, size_t ws_size,
                              hipStream_t stream) {
    (void)in_sizes; (void)n_in; (void)out_size; (void)ws_size;
    const float* adj      = (const float*)d_in[0];   // (T,N,N)
    const float* inp      = (const float*)d_in[1];   // (B,T,N,FI)
    const float* att_mask = (const float*)d_in[2];   // (B,N,T)
    const float* W        = (const float*)d_in[3];   // (FI,FO)
    const float* a        = (const float*)d_in[4];   // (2*FO,1)
    float* out = (float*)d_out;

    __bf16* hT  = (__bf16*)d_ws;                             // 32*16*4096 bf16 = 4 MB
    float*  s1w = (float*)((char*)d_ws + (size_t)4 * 1024 * 1024);
    float*  s2w = s1w + 32 * N_NODES;

    gat_h_kernel<<<512, 256, 0, stream>>>(inp, W, a, att_mask, hT, s1w, s2w);
    dim3 grid(64, 32);
    gat_attn_kernel<<<grid, 64, 0, stream>>>(adj, att_mask, hT, s1w, s2w, out);
}

// Round 9
// 138.738 us; speedup vs baseline: 1.4081x; 1.4081x over previous
//
#include <hip/hip_runtime.h>
#include <hip/hip_bf16.h>
#include <math.h>

#define N_NODES 1024
#define T_DIM 8

typedef __bf16 bf16x8 __attribute__((ext_vector_type(8)));
typedef float  f32x4  __attribute__((ext_vector_type(4)));

__device__ __forceinline__ float readlane_f(float v, int l) {
    return __uint_as_float(__builtin_amdgcn_readlane(__float_as_uint(v), l));
}

// ---- Kernel A: h = inp@W ; s1,s2 ; write hT = (h * mask_j) bf16 [bt][o][n] ---
// mask_j folded here: hT is only consumed as V in kernel B's PV matmul, and the
// softmax denominator must be unmasked (reference masks AFTER softmax).
__global__ __launch_bounds__(256) void gat_h_kernel(
    const float* __restrict__ inp, const float* __restrict__ W,
    const float* __restrict__ a, const float* __restrict__ att_mask,
    __bf16* __restrict__ hT, float* __restrict__ s1w, float* __restrict__ s2w)
{
    __shared__ float Wl[64 * 64];
    __shared__ float xl[64 * 64];
    __shared__ __bf16 htl[64 * 66];   // [o][row], stride 66 -> conflict-free transpose

    const int tid  = threadIdx.x;
    const int blk  = blockIdx.x;
    const int bt   = blk >> 4;
    const int b    = bt >> 3;
    const int t    = bt & 7;
    const int n0   = (blk & 15) * 64;
    const int lane = tid & 63;        // = o in compute phase
    const int wave = tid >> 6;

    const float4* W4  = (const float4*)W;
    float4*       Wl4 = (float4*)Wl;
    const float4* x4  = (const float4*)(inp + (size_t)(bt * N_NODES + n0) * 64);
    float4*       xl4 = (float4*)xl;
#pragma unroll
    for (int k = 0; k < 4; ++k) {
        Wl4[tid + k * 256] = W4[tid + k * 256];
        xl4[tid + k * 256] = x4[tid + k * 256];
    }
    const float a1 = a[lane];
    const float a2 = a[64 + lane];
    __syncthreads();

#pragma unroll 1
    for (int rg = 0; rg < 16; rg += 4) {
        float xr[4], acc[4];
#pragma unroll
        for (int q = 0; q < 4; ++q) {
            xr[q]  = xl[(wave * 16 + rg + q) * 64 + lane];
            acc[q] = 0.f;
        }
#pragma unroll
        for (int f = 0; f < 64; ++f) {
            float w = Wl[f * 64 + lane];
#pragma unroll
            for (int q = 0; q < 4; ++q)
                acc[q] = fmaf(readlane_f(xr[q], f), w, acc[q]);
        }
#pragma unroll
        for (int q = 0; q < 4; ++q) {
            const int r = wave * 16 + rg + q;   // local row
            float v1 = acc[q] * a1, v2 = acc[q] * a2;
#pragma unroll
            for (int off = 32; off; off >>= 1) {
                v1 += __shfl_xor(v1, off, 64);
                v2 += __shfl_xor(v2, off, 64);
            }
            if (lane == 0) {
                s1w[bt * N_NODES + n0 + r] = v1;
                s2w[bt * N_NODES + n0 + r] = v2;
            }
            const float mjr = att_mask[((size_t)b * N_NODES + n0 + r) * T_DIM + t];
            htl[lane * 66 + r] = (__bf16)(acc[q] * mjr);
        }
    }
    __syncthreads();

    // write hT[bt][o][n0+r0..+16] coalesced (thread: o = tid>>2, r0 = (tid&3)*16)
    {
        const int o  = tid >> 2;
        const int r0 = (tid & 3) * 16;
        unsigned u[8];
#pragma unroll
        for (int k = 0; k < 8; ++k)
            u[k] = *(const unsigned*)&htl[o * 66 + r0 + 2 * k];
        uint4* dst = (uint4*)(hT + (size_t)(bt * 64 + o) * N_NODES + n0 + r0);
        dst[0] = make_uint4(u[0], u[1], u[2], u[3]);
        dst[1] = make_uint4(u[4], u[5], u[6], u[7]);
    }
}

// ---- Kernel B: r4 barrier-free one-wave flash GAT + staggered j-phase -------
// grid (64 i-tiles, 32 bt) x 64 thr. Wave owns 16 rows, all 64 outputs, 16
// j-tiles. NEW: each block starts its j-sweep at phase = (blockIdx.x + 4b)&15,
// so i-blocks / b-siblings never gang-read the same h-tile lines or adj rows
// simultaneously (de-correlates L2 hot-line contention). Otherwise identical
// to the measured-best r4 body: h B-frags direct from global, adj coalesced
// (lane=j), P via wave-private LDS, 1-tile register prefetch, no barriers.
__global__ __launch_bounds__(64) void gat_attn_kernel(
    const float* __restrict__ adj, const float* __restrict__ att_mask,
    const __bf16* __restrict__ hT, const float* __restrict__ s1w,
    const float* __restrict__ s2w, float* __restrict__ out)
{
    __shared__ __align__(16) __bf16 p_l[16 * 72];   // [row][j], pad 72

    const int bt    = blockIdx.y;
    const int b     = bt >> 3;
    const int t     = bt & 7;
    const int irow0 = blockIdx.x * 16;
    const int lane  = threadIdx.x;      // = j within tile
    const int phase = (blockIdx.x + 4 * b) & 15;

    f32x4 acc[4];
#pragma unroll
    for (int nc = 0; nc < 4; ++nc) acc[nc] = (f32x4){0.f, 0.f, 0.f, 0.f};
    float lsum[16], s1v[16];
#pragma unroll
    for (int r = 0; r < 16; ++r) {
        lsum[r] = 0.f;
        s1v[r]  = s1w[bt * N_NODES + irow0 + r];
    }

    const float*  adjrow = adj + (size_t)t * N_NODES * N_NODES
                               + (size_t)irow0 * N_NODES + lane;
    const __bf16* hlane  = hT + (size_t)bt * 64 * N_NODES
                              + (size_t)(lane & 15) * N_NODES + (lane >> 4) * 8;
    const float*  s2bt   = s2w + bt * N_NODES;
    __bf16* pwr = p_l + lane;                                      // score write
    const __bf16* prd = p_l + (lane & 15) * 72 + (lane >> 4) * 8;  // A-frag read

    // ---- preload tile `phase` ----
    float  adjc[16];
    bf16x8 hc[8];
    float  s2c;
    const int jc0 = phase * 64;
#pragma unroll
    for (int r = 0; r < 16; ++r) adjc[r] = adjrow[(size_t)r * N_NODES + jc0];
#pragma unroll
    for (int kc = 0; kc < 2; ++kc)
#pragma unroll
        for (int nc = 0; nc < 4; ++nc)
            hc[kc * 4 + nc] = *(const bf16x8*)(hlane + (size_t)nc * 16 * N_NODES + jc0 + kc * 32);
    s2c = s2bt[jc0 + lane];

#pragma unroll 2
    for (int it = 0; it < 16; ++it) {
        const int jn = ((it + 1 + phase) & 15) * 64;   // next tile (ring walk)

        // ---- prefetch next tile into shadow registers ----
        float  adjn[16];
        bf16x8 hn[8];
#pragma unroll
        for (int r = 0; r < 16; ++r) adjn[r] = adjrow[(size_t)r * N_NODES + jn];
#pragma unroll
        for (int kc = 0; kc < 2; ++kc)
#pragma unroll
            for (int nc = 0; nc < 4; ++nc)
                hn[kc * 4 + nc] = *(const bf16x8*)(hlane + (size_t)nc * 16 * N_NODES + jn + kc * 32);
        const float s2n = s2bt[jn + lane];

        // ---- scores for current tile (lane = j); leaky bounds e*adj in
        // [-6,~16] so exp never overflows -> no max pass needed ----
#pragma unroll
        for (int r = 0; r < 16; ++r) {
            float e = s1v[r] + s2c;
            e = fmaxf(e, 0.2f * e);
            float p = (adjc[r] > 0.f) ? __expf(e * adjc[r]) : 0.f;
            lsum[r] += p;
            pwr[r * 72] = (__bf16)p;
        }

        // ---- P -> A-frag via wave-private LDS, then 8 MFMAs ----
        bf16x8 af0 = *(const bf16x8*)(prd);
        bf16x8 af1 = *(const bf16x8*)(prd + 32);
#pragma unroll
        for (int nc = 0; nc < 4; ++nc)
            acc[nc] = __builtin_amdgcn_mfma_f32_16x16x32_bf16(af0, hc[nc], acc[nc], 0, 0, 0);
#pragma unroll
        for (int nc = 0; nc < 4; ++nc)
            acc[nc] = __builtin_amdgcn_mfma_f32_16x16x32_bf16(af1, hc[4 + nc], acc[nc], 0, 0, 0);

        // ---- rotate prefetch buffers (unroll-2 renames the copies away) ----
#pragma unroll
        for (int r = 0; r < 16; ++r) adjc[r] = adjn[r];
#pragma unroll
        for (int k = 0; k < 8; ++k) hc[k] = hn[k];
        s2c = s2n;
    }

    // ---- epilogue: reduce lsum once, mi/ls scale + ELU + store ----
#pragma unroll
    for (int r = 0; r < 16; ++r) {
#pragma unroll
        for (int off = 32; off; off >>= 1)
            lsum[r] += __shfl_xor(lsum[r], off, 64);
    }
    const int q = lane >> 4;
#pragma unroll
    for (int reg = 0; reg < 4; ++reg) {
        float ls = (q == 0) ? lsum[reg] : (q == 1) ? lsum[4 + reg]
                 : (q == 2) ? lsum[8 + reg] : lsum[12 + reg];
        const int i = irow0 + q * 4 + reg;
        float mi    = att_mask[((size_t)b * N_NODES + i) * T_DIM + t];
        float scale = mi / ls;
#pragma unroll
        for (int nc = 0; nc < 4; ++nc) {
            float v = acc[nc][reg] * scale;
            v = (v > 0.f) ? v : (__expf(v) - 1.f);
            out[((size_t)bt * N_NODES + i) * 64 + nc * 16 + (lane & 15)] = v;
        }
    }
}

extern "C" void kernel_launch(void* const* d_in, const int* in_sizes, int n_in,
                              void* d_out, int out_size, void* d_ws, size_t ws_size,
                              hipStream_t stream) {
    (void)in_sizes; (void)n_in; (void)out_size; (void)ws_size;
    const float* adj      = (const float*)d_in[0];   // (T,N,N)
    const float* inp      = (const float*)d_in[1];   // (B,T,N,FI)
    const float* att_mask = (const float*)d_in[2];   // (B,N,T)
    const float* W        = (const float*)d_in[3];   // (FI,FO)
    const float* a        = (const float*)d_in[4];   // (2*FO,1)
    float* out = (float*)d_out;

    __bf16* hT  = (__bf16*)d_ws;                             // 32*64*1024 bf16 = 4 MB
    float*  s1w = (float*)((char*)d_ws + (size_t)4 * 1024 * 1024);
    float*  s2w = s1w + 32 * N_NODES;

    gat_h_kernel<<<512, 256, 0, stream>>>(inp, W, a, att_mask, hT, s1w, s2w);
    dim3 grid(64, 32);
    gat_attn_kernel<<<grid, 64, 0, stream>>>(adj, att_mask, hT, s1w, s2w, out);
}